// Round 11
// baseline (287.450 us; speedup 1.0000x reference)
//
#include <hip/hip_runtime.h>

typedef unsigned short ushort_t;
typedef unsigned long long u64_t;
typedef __attribute__((ext_vector_type(8))) short v8bf;
typedef __attribute__((ext_vector_type(8))) unsigned short v8us;
typedef __attribute__((ext_vector_type(4))) float v4f;

#define BROWS 4096
#define DIMK 256
#define QN 32768
#define EXPSCALE 14.426950408889634f   // 10 * log2(e)

__device__ __forceinline__ ushort_t f2bf(float f) {
    unsigned u = __float_as_uint(f);
    return (ushort_t)((u + 0x7FFFu + ((u >> 16) & 1u)) >> 16);   // RNE
}
__device__ __forceinline__ u64_t shfl_xor_u64(u64_t v, int off) {
    unsigned lo = (unsigned)(v & 0xFFFFFFFFull);
    unsigned hi = (unsigned)(v >> 32);
    lo = (unsigned)__shfl_xor((int)lo, off, 64);
    hi = (unsigned)__shfl_xor((int)hi, off, 64);
    return ((u64_t)hi << 32) | (u64_t)lo;
}
#define GLOAD(g, l_) __builtin_amdgcn_global_load_lds(                         \
    (const __attribute__((address_space(1))) void*)(g),                        \
    (__attribute__((address_space(3))) void*)(l_), 16, 0, 0)

// ---- bf16 conversion of the queue ----
__global__ __launch_bounds__(256) void conv_bf16(const float* __restrict__ in,
                                                 ushort_t* __restrict__ out) {
    const size_t i = ((size_t)blockIdx.x * 256 + threadIdx.x) * 8;
    float4 x = *(const float4*)&in[i];
    float4 y = *(const float4*)&in[i + 4];
    v8us o;
    o[0] = f2bf(x.x); o[1] = f2bf(x.y); o[2] = f2bf(x.z); o[3] = f2bf(x.w);
    o[4] = f2bf(y.x); o[5] = f2bf(y.y); o[6] = f2bf(y.z); o[7] = f2bf(y.w);
    *(v8us*)&out[i] = o;
}

// ---- fused two-layer projection + L2 norm (16 rows/block, grid.y = f1/f2) ----
__global__ __launch_bounds__(256) void proj_fused(const float* __restrict__ F1,
                                                  const float* __restrict__ F2,
                                                  const float* __restrict__ W1,
                                                  const float* __restrict__ b1,
                                                  const float* __restrict__ W2,
                                                  const float* __restrict__ b2,
                                                  ushort_t* __restrict__ P) {
    __shared__ float fr[16][256];
    __shared__ float hr[16][256];
    __shared__ float partial[4][16];
    const float* F = blockIdx.y ? F2 : F1;
    ushort_t* Po = P + (size_t)blockIdx.y * BROWS * DIMK;
    const int r0 = blockIdx.x << 4, j = threadIdx.x;
    const int w = j >> 6, l = j & 63;
#pragma unroll
    for (int r = 0; r < 16; ++r) fr[r][j] = F[(size_t)(r0 + r) * DIMK + j];
    __syncthreads();
    float acc[16];
    // layer 1: h = relu(F W1 + b1)
    {
        const float bj = b1[j];
#pragma unroll
        for (int r = 0; r < 16; ++r) acc[r] = bj;
        for (int k = 0; k < DIMK; k += 4) {
            const float w0 = W1[(k + 0) * DIMK + j];
            const float w1 = W1[(k + 1) * DIMK + j];
            const float w2 = W1[(k + 2) * DIMK + j];
            const float w3 = W1[(k + 3) * DIMK + j];
#pragma unroll
            for (int r = 0; r < 16; ++r) {
                float4 f = *(const float4*)&fr[r][k];
                acc[r] = fmaf(f.x, w0, acc[r]);
                acc[r] = fmaf(f.y, w1, acc[r]);
                acc[r] = fmaf(f.z, w2, acc[r]);
                acc[r] = fmaf(f.w, w3, acc[r]);
            }
        }
#pragma unroll
        for (int r = 0; r < 16; ++r) hr[r][j] = acc[r] > 0.f ? acc[r] : 0.f;
    }
    __syncthreads();
    // layer 2: p = h W2 + b2, then row-L2-normalize
    {
        const float bj = b2[j];
#pragma unroll
        for (int r = 0; r < 16; ++r) acc[r] = bj;
        for (int k = 0; k < DIMK; k += 4) {
            const float w0 = W2[(k + 0) * DIMK + j];
            const float w1 = W2[(k + 1) * DIMK + j];
            const float w2 = W2[(k + 2) * DIMK + j];
            const float w3 = W2[(k + 3) * DIMK + j];
#pragma unroll
            for (int r = 0; r < 16; ++r) {
                float4 f = *(const float4*)&hr[r][k];
                acc[r] = fmaf(f.x, w0, acc[r]);
                acc[r] = fmaf(f.y, w1, acc[r]);
                acc[r] = fmaf(f.z, w2, acc[r]);
                acc[r] = fmaf(f.w, w3, acc[r]);
            }
        }
    }
#pragma unroll
    for (int r = 0; r < 16; ++r) {
        float s = acc[r] * acc[r];
        s += __shfl_xor(s, 1);  s += __shfl_xor(s, 2);
        s += __shfl_xor(s, 4);  s += __shfl_xor(s, 8);
        s += __shfl_xor(s, 16); s += __shfl_xor(s, 32);
        if (l == 0) partial[w][r] = s;
    }
    __syncthreads();
#pragma unroll
    for (int r = 0; r < 16; ++r) {
        const float tot = partial[0][r] + partial[1][r] + partial[2][r] + partial[3][r];
        const float inv = 1.f / fmaxf(sqrtf(tot), 1e-12f);
        Po[(size_t)(r0 + r) * DIMK + j] = f2bf(acc[r] * inv);
    }
}

// ---- stage a 128-row x 256-k bf16 panel into 64KB LDS (64 segs of 1KB).
// LDS dest linear (gload_lds HW); global source pre-swizzled: 16B slot s of
// row r holds logical octet (s&~7)|((s&7)^(r&7)).
__device__ __forceinline__ void stage_panel(const ushort_t* __restrict__ M, int grow0,
                                            ushort_t* lds, int w, int l) {
#pragma unroll
    for (int j = 0; j < 16; ++j) {
        const int seg = (j << 2) + w;              // 1KB segment 0..63
        const int row = (seg << 1) + (l >> 5);     // 512B rows
        const int s = l & 31;
        const int oct = (s & ~7) | ((s & 7) ^ (row & 7));
        GLOAD(&M[(size_t)(grow0 + row) * DIMK + (oct << 3)], lds + (seg << 9));
    }
}

// ---- persistent-block GEMM, A FRAGMENTS IN REGISTERS (areg 128 VGPR).
// Block 128 rows x 128-col tiles, 4 waves (2Mx2N), wave tile 64x64.
// A panel staged to LDS once -> read into areg -> LDS region reused for the
// full per-t B panel (128 cols x 256 k, 64KB) => 2 barriers per t (was 8),
// LDS reads per k0 halved (B only). LDS 64KB, VGPR ~245 -> 2 blocks/CU.
// MODE 0: fused argmax, 512 blocks, NT=32. Argmax packs (25-bit value | t | nj)
// into one u32 -> 16 regs of state.
// MODE 1: exp-sums + diag, 512 blocks, NT=4, plain-store partials.
// NOTE: min-waves stays 2 (R7: 3 forced VGPR<=84 -> acc spilled, 5x slowdown).
template <int MODE, int NT>
__global__ __launch_bounds__(256, 2) void nn_lse(const ushort_t* __restrict__ Abase,
                                                 const ushort_t* __restrict__ Bbase,
                                                 u64_t* __restrict__ packed,
                                                 float* __restrict__ srp,
                                                 float* __restrict__ scp,
                                                 float* __restrict__ diag) {
    __shared__ __align__(16) ushort_t Lds[128 * 256];   // 64 KB: A once, then B/t
    const int tid = threadIdx.x;
    const int w = tid >> 6, l = tid & 63;
    const int wr = w >> 1, wc = w & 1;   // wave tile 64x64

    int arow0, colbase, rowblk = 0, colstrip = 0, z = 0;
    const ushort_t* A; const ushort_t* B;
    u64_t* pk_out = nullptr;
    float* dg = nullptr;
    if (MODE == 0) {
        const int bid = blockIdx.x;                // 512 blocks, all resident
        const int xcd = bid & 7, i = bid >> 3;     // i in 0..63
        const int half = xcd & 1;
        const int pairgrp = xcd >> 1;              // owns 8192 cols
        arow0 = (i & 31) << 7;                     // 32 row-blocks of 128
        colbase = (pairgrp << 13) + ((i >> 5) << 12);   // + col-half*4096
        A = Abase + (size_t)half * BROWS * DIMK;
        B = Bbase;
        pk_out = packed + (size_t)half * BROWS;
    } else {
        z = blockIdx.x >> 8;
        const int i = blockIdx.x & 255;
        rowblk = i & 31;
        colstrip = i >> 5;                         // 8 strips of 512 cols
        arow0 = rowblk << 7;
        colbase = colstrip << 9;
        A = Abase + (size_t)z * BROWS * DIMK;
        B = Bbase + (size_t)(1 - z) * BROWS * DIMK;
        dg = diag + (size_t)z * BROWS;
    }

    // ---- prologue: A panel -> LDS -> registers (all indices compile-time)
    stage_panel(A, arow0, (ushort_t*)Lds, w, l);
    __syncthreads();
    v8bf areg[4][8];   // [mi][(k0<<1)+hh]
#pragma unroll
    for (int mi = 0; mi < 4; ++mi)
#pragma unroll
        for (int j = 0; j < 8; ++j) {
            const int row = (wr << 6) + (mi << 4) + (l & 15);
            const int lo = ((j & 1) << 2) + (l >> 4);
            const int phys = ((j >> 1) << 3) | (lo ^ (row & 7));
            areg[mi][j] = *(const v8bf*)&Lds[(row << 8) + (phys << 3)];
        }
    __syncthreads();   // all waves done reading A region before B overwrites

    unsigned best[4][4];
    float rsum[4][4];
#pragma unroll
    for (int a = 0; a < 4; ++a)
#pragma unroll
        for (int r = 0; r < 4; ++r) { best[a][r] = 0u; rsum[a][r] = 0.f; }

    for (int t = 0; t < NT; ++t) {
        // stage the full B panel for this tile (128 cols x 256 k)
        stage_panel(B, colbase + (t << 7), (ushort_t*)Lds, w, l);
        __syncthreads();   // drains vmcnt: panel resident

        v4f acc[4][4];
        const float cinit = (MODE == 0) ? 2.0f : 0.0f;   // +2 -> positive, uint-monotone
#pragma unroll
        for (int a = 0; a < 4; ++a)
#pragma unroll
            for (int b = 0; b < 4; ++b) acc[a][b] = (v4f){cinit, cinit, cinit, cinit};

#pragma unroll
        for (int k0 = 0; k0 < 4; ++k0)
#pragma unroll
            for (int hh = 0; hh < 2; ++hh) {
                v8bf bv[4];
#pragma unroll
                for (int nj = 0; nj < 4; ++nj) {
                    const int row = (wc << 6) + (nj << 4) + (l & 15);
                    const int lo = (hh << 2) + (l >> 4);
                    const int phys = (k0 << 3) | (lo ^ (row & 7));
                    bv[nj] = *(const v8bf*)&Lds[(row << 8) + (phys << 3)];
                }
#pragma unroll
                for (int mi = 0; mi < 4; ++mi)
#pragma unroll
                    for (int nj = 0; nj < 4; ++nj)
                        acc[mi][nj] = __builtin_amdgcn_mfma_f32_16x16x32_bf16(
                            areg[mi][(k0 << 1) + hh], bv[nj], acc[mi][nj], 0, 0, 0);
            }
        __syncthreads();   // all reads done: Lds free for next t

        if (MODE == 0) {
            // running argmax: (bits(v+2) & 0xFFFFFF80) | (t<<2) | nj, uint-max
#pragma unroll
            for (int mi = 0; mi < 4; ++mi)
#pragma unroll
                for (int r = 0; r < 4; ++r) {
                    unsigned m = (__float_as_uint(acc[mi][0][r]) & 0xFFFFFF80u) |
                                 ((unsigned)t << 2);
#pragma unroll
                    for (int nj = 1; nj < 4; ++nj) {
                        unsigned c = (__float_as_uint(acc[mi][nj][r]) & 0xFFFFFF80u) |
                                     ((unsigned)t << 2) | (unsigned)nj;
                        m = c > m ? c : m;
                    }
                    if (m > best[mi][r]) best[mi][r] = m;
                }
        } else {
            const int cb = colbase + (t << 7);
            // diag from raw scores (before exp); unique writer per cell
#pragma unroll
            for (int mi = 0; mi < 4; ++mi)
#pragma unroll
                for (int nj = 0; nj < 4; ++nj) {
                    const int gr16 = arow0 + (wr << 6) + (mi << 4);
                    const int gc16 = cb + (wc << 6) + (nj << 4);
                    if (gr16 == gc16) {
#pragma unroll
                        for (int r = 0; r < 4; ++r) {
                            const int rr = ((l >> 4) << 2) + r;
                            if ((l & 15) == rr) dg[gr16 + rr] = acc[mi][nj][r] * 10.0f;
                        }
                    }
                }
#pragma unroll
            for (int mi = 0; mi < 4; ++mi)
#pragma unroll
                for (int nj = 0; nj < 4; ++nj) {
                    v4f tv = acc[mi][nj];
                    tv[0] = exp2f(tv[0] * EXPSCALE);
                    tv[1] = exp2f(tv[1] * EXPSCALE);
                    tv[2] = exp2f(tv[2] * EXPSCALE);
                    tv[3] = exp2f(tv[3] * EXPSCALE);
                    acc[mi][nj] = tv;
                }
#pragma unroll
            for (int mi = 0; mi < 4; ++mi)
#pragma unroll
                for (int r = 0; r < 4; ++r) {
                    float s = 0.f;
#pragma unroll
                    for (int nj = 0; nj < 4; ++nj) s += acc[mi][nj][r];
                    rsum[mi][r] += s;
                }
            // col partials: unique strip (z,rowblk,wr); plain stores
#pragma unroll
            for (int nj = 0; nj < 4; ++nj) {
                float s = 0.f;
#pragma unroll
                for (int mi = 0; mi < 4; ++mi)
#pragma unroll
                    for (int r = 0; r < 4; ++r) s += acc[mi][nj][r];
                s += __shfl_xor(s, 16); s += __shfl_xor(s, 32);
                if (l < 16)
                    scp[((size_t)(z << 6) + (rowblk << 1) + wr) * BROWS +
                        cb + (wc << 6) + (nj << 4) + l] = s;
            }
        }
    }

    if (MODE == 0) {
#pragma unroll
        for (int mi = 0; mi < 4; ++mi)
#pragma unroll
            for (int r = 0; r < 4; ++r) {
                const unsigned wb = best[mi][r];
                const unsigned col = (unsigned)(colbase + (int)(((wb >> 2) & 31u) << 7) +
                                                (wc << 6) + (int)((wb & 3u) << 4)) + (l & 15);
                u64_t pk = ((u64_t)wb << 32) | (u64_t)(0xFFFFFFFFu - col);
#pragma unroll
                for (int off = 1; off < 16; off <<= 1) {
                    u64_t o = shfl_xor_u64(pk, off);
                    if (o > pk) pk = o;
                }
                if ((l & 15) == 0)
                    atomicMax(&pk_out[arow0 + (wr << 6) + (mi << 4) + ((l >> 4) << 2) + r], pk);
            }
    } else {
        // row partials: unique strip (z, colstrip, wc); plain stores
#pragma unroll
        for (int mi = 0; mi < 4; ++mi)
#pragma unroll
            for (int r = 0; r < 4; ++r) {
                float s = rsum[mi][r];
                s += __shfl_xor(s, 1); s += __shfl_xor(s, 2);
                s += __shfl_xor(s, 4); s += __shfl_xor(s, 8);
                if ((l & 15) == 0)
                    srp[((size_t)(z << 4) + (colstrip << 1) + wc) * BROWS +
                        arow0 + (wr << 6) + (mi << 4) + ((l >> 4) << 2) + r] = s;
            }
    }
}

// ---- fold partial strips into sums[4][BROWS] ----
__global__ __launch_bounds__(256) void reduce_sums(const float* __restrict__ srp,
                                                   const float* __restrict__ scp,
                                                   float* __restrict__ sums) {
    const int idx = blockIdx.x * 256 + threadIdx.x;   // 8192
    const int z = idx >> 12, row = idx & 4095;
    float a = 0.f, b = 0.f;
#pragma unroll 4
    for (int s = 0; s < 16; ++s) a += srp[((size_t)(z << 4) + s) * BROWS + row];
#pragma unroll 4
    for (int s = 0; s < 64; ++s) b += scp[((size_t)(z << 6) + s) * BROWS + row];
    sums[(size_t)(2 * z) * BROWS + row] = a;
    sums[(size_t)(2 * z + 1) * BROWS + row] = b;
}

// ---- gather nn rows (grid-stride) ----
__global__ __launch_bounds__(256) void gather_bf(const u64_t* __restrict__ packed,
                                                 const ushort_t* __restrict__ qb,
                                                 ushort_t* __restrict__ nn) {
    const int j = threadIdx.x;
    for (int i = blockIdx.x; i < 2 * BROWS; i += (int)gridDim.x) {
        const unsigned idx = 0xFFFFFFFFu - (unsigned)(packed[i] & 0xFFFFFFFFull);
        nn[(size_t)i * DIMK + j] = qb[(size_t)idx * DIMK + j];
    }
}

__global__ __launch_bounds__(256) void final_loss(const float* __restrict__ d1,
                                                  const float* __restrict__ d2,
                                                  const float* __restrict__ sr1,
                                                  const float* __restrict__ sc1,
                                                  const float* __restrict__ sr2,
                                                  const float* __restrict__ sc2,
                                                  float* __restrict__ out) {
    __shared__ float red[256];
    const int t = threadIdx.x;
    float acc = 0.f;
    for (int i = t; i < BROWS; i += 256) {
        acc += 2.f * (d1[i] + d2[i]) - logf(sr1[i]) - logf(sc1[i]) - logf(sr2[i]) - logf(sc2[i]);
    }
    red[t] = acc;
    __syncthreads();
    for (int s = 128; s > 0; s >>= 1) {
        if (t < s) red[t] += red[t + s];
        __syncthreads();
    }
    if (t == 0) out[0] = -red[0] / (4.0f * (float)BROWS);
}

extern "C" void kernel_launch(void* const* d_in, const int* in_sizes, int n_in,
                              void* d_out, int out_size, void* d_ws, size_t ws_size,
                              hipStream_t stream) {
    const float* f1 = (const float*)d_in[0];
    const float* f2 = (const float*)d_in[1];
    const float* W1 = (const float*)d_in[2];
    const float* b1 = (const float*)d_in[3];
    const float* W2 = (const float*)d_in[4];
    const float* b2 = (const float*)d_in[5];
    const float* queue = (const float*)d_in[6];
    float* out = (float*)d_out;

    char* ws = (char*)d_ws;
    ushort_t* pcat  = (ushort_t*)(ws + (8ull << 20));      // 4 MB: p1 | p2
    ushort_t* nncat = (ushort_t*)(ws + (12ull << 20));     // 4 MB: nn1 | nn2
    ushort_t* qb    = (ushort_t*)(ws + (16ull << 20));     // 16 MB
    u64_t* packed   = (u64_t*)(ws + (32ull << 20));        // 64 KB (8192 rows)
    float* sums     = (float*)(ws + (32ull << 20) + (64ull << 10));    // 64 KB
    float* diag     = (float*)(ws + (32ull << 20) + (128ull << 10));   // 32 KB
    float* srp      = (float*)(ws + (32ull << 20) + (160ull << 10));   // 512 KB [2][16][4096]
    float* scp      = (float*)(ws + (32ull << 20) + (672ull << 10));   // 2 MB  [2][64][4096]

    // zero only the argmax atomic targets
    hipMemsetAsync(packed, 0, (64ull << 10), stream);

    conv_bf16<<<(QN * DIMK) / 2048, 256, 0, stream>>>(queue, qb);

    dim3 gp(BROWS / 16, 2);
    proj_fused<<<gp, 256, 0, stream>>>(f1, f2, W1, b1, W2, b2, pcat);

    nn_lse<0, 32><<<512, 256, 0, stream>>>(pcat, qb, packed, nullptr, nullptr, nullptr);

    gather_bf<<<256, 256, 0, stream>>>(packed, qb, nncat);

    nn_lse<1, 4><<<512, 256, 0, stream>>>(nncat, pcat, nullptr, srp, scp, diag);

    reduce_sums<<<32, 256, 0, stream>>>(srp, scp, sums);

    final_loss<<<1, 256, 0, stream>>>(diag, diag + BROWS,
                                      sums, sums + BROWS, sums + 2 * BROWS, sums + 3 * BROWS,
                                      out);
}

// Round 12
// 264.683 us; speedup vs baseline: 1.0860x; 1.0860x over previous
//
#include <hip/hip_runtime.h>

typedef unsigned short ushort_t;
typedef unsigned long long u64_t;
typedef __attribute__((ext_vector_type(8))) short v8bf;
typedef __attribute__((ext_vector_type(8))) unsigned short v8us;
typedef __attribute__((ext_vector_type(4))) float v4f;

#define BROWS 4096
#define DIMK 256
#define QN 32768
#define EXPSCALE 14.426950408889634f   // 10 * log2(e)

__device__ __forceinline__ ushort_t f2bf(float f) {
    unsigned u = __float_as_uint(f);
    return (ushort_t)((u + 0x7FFFu + ((u >> 16) & 1u)) >> 16);   // RNE
}
__device__ __forceinline__ u64_t shfl_xor_u64(u64_t v, int off) {
    unsigned lo = (unsigned)(v & 0xFFFFFFFFull);
    unsigned hi = (unsigned)(v >> 32);
    lo = (unsigned)__shfl_xor((int)lo, off, 64);
    hi = (unsigned)__shfl_xor((int)hi, off, 64);
    return ((u64_t)hi << 32) | (u64_t)lo;
}
#define GLOAD(g, l_) __builtin_amdgcn_global_load_lds(                         \
    (const __attribute__((address_space(1))) void*)(g),                        \
    (__attribute__((address_space(3))) void*)(l_), 16, 0, 0)

// ---- bf16 conversion of the queue ----
__global__ __launch_bounds__(256) void conv_bf16(const float* __restrict__ in,
                                                 ushort_t* __restrict__ out) {
    const size_t i = ((size_t)blockIdx.x * 256 + threadIdx.x) * 8;
    float4 x = *(const float4*)&in[i];
    float4 y = *(const float4*)&in[i + 4];
    v8us o;
    o[0] = f2bf(x.x); o[1] = f2bf(x.y); o[2] = f2bf(x.z); o[3] = f2bf(x.w);
    o[4] = f2bf(y.x); o[5] = f2bf(y.y); o[6] = f2bf(y.z); o[7] = f2bf(y.w);
    *(v8us*)&out[i] = o;
}

// ---- fused two-layer projection + L2 norm (16 rows/block, grid.y = f1/f2) ----
__global__ __launch_bounds__(256) void proj_fused(const float* __restrict__ F1,
                                                  const float* __restrict__ F2,
                                                  const float* __restrict__ W1,
                                                  const float* __restrict__ b1,
                                                  const float* __restrict__ W2,
                                                  const float* __restrict__ b2,
                                                  ushort_t* __restrict__ P) {
    __shared__ float fr[16][256];
    __shared__ float hr[16][256];
    __shared__ float partial[4][16];
    const float* F = blockIdx.y ? F2 : F1;
    ushort_t* Po = P + (size_t)blockIdx.y * BROWS * DIMK;
    const int r0 = blockIdx.x << 4, j = threadIdx.x;
    const int w = j >> 6, l = j & 63;
#pragma unroll
    for (int r = 0; r < 16; ++r) fr[r][j] = F[(size_t)(r0 + r) * DIMK + j];
    __syncthreads();
    float acc[16];
    {
        const float bj = b1[j];
#pragma unroll
        for (int r = 0; r < 16; ++r) acc[r] = bj;
        for (int k = 0; k < DIMK; k += 4) {
            const float w0 = W1[(k + 0) * DIMK + j];
            const float w1 = W1[(k + 1) * DIMK + j];
            const float w2 = W1[(k + 2) * DIMK + j];
            const float w3 = W1[(k + 3) * DIMK + j];
#pragma unroll
            for (int r = 0; r < 16; ++r) {
                float4 f = *(const float4*)&fr[r][k];
                acc[r] = fmaf(f.x, w0, acc[r]);
                acc[r] = fmaf(f.y, w1, acc[r]);
                acc[r] = fmaf(f.z, w2, acc[r]);
                acc[r] = fmaf(f.w, w3, acc[r]);
            }
        }
#pragma unroll
        for (int r = 0; r < 16; ++r) hr[r][j] = acc[r] > 0.f ? acc[r] : 0.f;
    }
    __syncthreads();
    {
        const float bj = b2[j];
#pragma unroll
        for (int r = 0; r < 16; ++r) acc[r] = bj;
        for (int k = 0; k < DIMK; k += 4) {
            const float w0 = W2[(k + 0) * DIMK + j];
            const float w1 = W2[(k + 1) * DIMK + j];
            const float w2 = W2[(k + 2) * DIMK + j];
            const float w3 = W2[(k + 3) * DIMK + j];
#pragma unroll
            for (int r = 0; r < 16; ++r) {
                float4 f = *(const float4*)&hr[r][k];
                acc[r] = fmaf(f.x, w0, acc[r]);
                acc[r] = fmaf(f.y, w1, acc[r]);
                acc[r] = fmaf(f.z, w2, acc[r]);
                acc[r] = fmaf(f.w, w3, acc[r]);
            }
        }
    }
#pragma unroll
    for (int r = 0; r < 16; ++r) {
        float s = acc[r] * acc[r];
        s += __shfl_xor(s, 1);  s += __shfl_xor(s, 2);
        s += __shfl_xor(s, 4);  s += __shfl_xor(s, 8);
        s += __shfl_xor(s, 16); s += __shfl_xor(s, 32);
        if (l == 0) partial[w][r] = s;
    }
    __syncthreads();
#pragma unroll
    for (int r = 0; r < 16; ++r) {
        const float tot = partial[0][r] + partial[1][r] + partial[2][r] + partial[3][r];
        const float inv = 1.f / fmaxf(sqrtf(tot), 1e-12f);
        Po[(size_t)(r0 + r) * DIMK + j] = f2bf(acc[r] * inv);
    }
}

// ---- stage a 128-row x 256-k bf16 panel into 64KB LDS (64 segs of 1KB).
// Global source pre-swizzled: 16B slot s of row r holds octet (s&~7)|((s&7)^(r&7)).
__device__ __forceinline__ void stage_panel(const ushort_t* __restrict__ M, int grow0,
                                            ushort_t* lds, int w, int l) {
#pragma unroll
    for (int j = 0; j < 16; ++j) {
        const int seg = (j << 2) + w;
        const int row = (seg << 1) + (l >> 5);
        const int s = l & 31;
        const int oct = (s & ~7) | ((s & 7) ^ (row & 7));
        GLOAD(&M[(size_t)(grow0 + row) * DIMK + (oct << 3)], lds + (seg << 9));
    }
}

// ---- stage a 128-col x 64-k B tile (16KB) ----
__device__ __forceinline__ void stage_b(const ushort_t* __restrict__ B, int col0,
                                        int kelem, ushort_t* dst, int w, int l) {
#pragma unroll
    for (int j = 0; j < 4; ++j) {
        const int seg = (j << 2) + w;
        const int row = (seg << 3) + (l >> 3);
        const int oct = (l & 7) ^ (row & 7);
        GLOAD(&B[(size_t)(col0 + row) * DIMK + kelem + (oct << 3)], dst + (seg << 9));
    }
}

// ---- persistent-block GEMM: A in REGISTERS, B double-buffered, 1 barrier/phase.
// Block 128 rows x 128-col tiles, 4 waves (2Mx2N), wave tile 64x64.
// LDS 64KB total: A panel during prologue, then 2x16KB B buffers (union).
// Phase p = t*4+k0: issue stage(p+1) -> buf[(p+1)&1]; read frags buf[p&1];
// 32 MFMA; single __syncthreads (drains in-flight stage + releases buffer).
// MODE 0: fused argmax, 512 blocks persistent, NT=32 (L2-exact decode, R9).
// MODE 1: exp-sums + diag, 512 blocks, NT=4, plain-store partials.
// NOTE: min-waves 2 (R7: 3 forced VGPR<=84 -> acc spill, 5x). VGPR ~240: if
// VGPR_Count=256 + big WRITE_SIZE, this experiment spilled -> revert.
template <int MODE, int NT>
__global__ __launch_bounds__(256, 2) void nn_lse(const ushort_t* __restrict__ Abase,
                                                 const ushort_t* __restrict__ Bbase,
                                                 u64_t* __restrict__ packed,
                                                 float* __restrict__ srp,
                                                 float* __restrict__ scp,
                                                 float* __restrict__ diag) {
    __shared__ __align__(16) ushort_t Lds[128 * 256];   // 64 KB
    const int tid = threadIdx.x;
    const int w = tid >> 6, l = tid & 63;
    const int wr = w >> 1, wc = w & 1;   // wave tile 64x64
    constexpr int NP = NT * 4;

    int arow0, colbase, rowblk = 0, colstrip = 0, z = 0;
    const ushort_t* A; const ushort_t* B;
    u64_t* pk_out = nullptr;
    float* dg = nullptr;
    if (MODE == 0) {
        const int bid = blockIdx.x;                // 512 blocks, all resident
        const int xcd = bid & 7, i = bid >> 3;
        const int half = xcd & 1;
        const int pairgrp = xcd >> 1;              // owns 8192 cols
        arow0 = (i & 31) << 7;
        colbase = (pairgrp << 13) + ((i >> 5) << 12);
        A = Abase + (size_t)half * BROWS * DIMK;
        B = Bbase;
        pk_out = packed + (size_t)half * BROWS;
    } else {
        z = blockIdx.x >> 8;
        const int i = blockIdx.x & 255;
        rowblk = i & 31;
        colstrip = i >> 5;
        arow0 = rowblk << 7;
        colbase = colstrip << 9;
        A = Abase + (size_t)z * BROWS * DIMK;
        B = Bbase + (size_t)(1 - z) * BROWS * DIMK;
        dg = diag + (size_t)z * BROWS;
    }

    // ---- prologue: A panel -> LDS -> registers (compile-time indices, rule #20)
    stage_panel(A, arow0, (ushort_t*)Lds, w, l);
    __syncthreads();
    v8bf areg[4][8];   // [mi][(k0<<1)+hh]  = 128 VGPR
#pragma unroll
    for (int mi = 0; mi < 4; ++mi)
#pragma unroll
        for (int j = 0; j < 8; ++j) {
            const int row = (wr << 6) + (mi << 4) + (l & 15);
            const int lo = ((j & 1) << 2) + (l >> 4);
            const int phys = ((j >> 1) << 3) | (lo ^ (row & 7));
            areg[mi][j] = *(const v8bf*)&Lds[(row << 8) + (phys << 3)];
        }
    __syncthreads();   // all waves done with A region

    ushort_t* buf0 = (ushort_t*)Lds;          // 16 KB
    ushort_t* buf1 = (ushort_t*)Lds + 8192;   // 16 KB

    // stage phase 0, drain
    stage_b(B, colbase, 0, buf0, w, l);
    __syncthreads();

    unsigned best[4][4];
    float rsum[4][4];
#pragma unroll
    for (int a = 0; a < 4; ++a)
#pragma unroll
        for (int r = 0; r < 4; ++r) { best[a][r] = 0u; rsum[a][r] = 0.f; }

    for (int t = 0; t < NT; ++t) {
        v4f acc[4][4];
        const float cinit = (MODE == 0) ? 2.0f : 0.0f;
#pragma unroll
        for (int a = 0; a < 4; ++a)
#pragma unroll
            for (int b = 0; b < 4; ++b) acc[a][b] = (v4f){cinit, cinit, cinit, cinit};

#pragma unroll
        for (int k0 = 0; k0 < 4; ++k0) {
            const int p = (t << 2) + k0;
            // issue next phase's stage into the other buffer (freed at p-1's sync)
            if (p + 1 < NP) {
                const int tn = (p + 1) >> 2, kn = (p + 1) & 3;
                stage_b(B, colbase + (tn << 7), kn << 6, (p & 1) ? buf0 : buf1, w, l);
            }
            const ushort_t* bufr = (p & 1) ? buf1 : buf0;
#pragma unroll
            for (int hh = 0; hh < 2; ++hh) {
                v8bf bv[4];
#pragma unroll
                for (int nj = 0; nj < 4; ++nj) {
                    const int row = (wc << 6) + (nj << 4) + (l & 15);
                    const int phys = ((hh << 2) + (l >> 4)) ^ (row & 7);
                    bv[nj] = *(const v8bf*)&bufr[(row << 6) + (phys << 3)];
                }
#pragma unroll
                for (int mi = 0; mi < 4; ++mi)
#pragma unroll
                    for (int nj = 0; nj < 4; ++nj)
                        acc[mi][nj] = __builtin_amdgcn_mfma_f32_16x16x32_bf16(
                            areg[mi][(k0 << 1) + hh], bv[nj], acc[mi][nj], 0, 0, 0);
            }
            __syncthreads();   // drains stage(p+1); all waves done reading bufr
        }

        if (MODE == 0) {
            // running argmax: (bits(v+2) & 0xFFFFFF80) | (t<<2) | nj, uint-max
#pragma unroll
            for (int mi = 0; mi < 4; ++mi)
#pragma unroll
                for (int r = 0; r < 4; ++r) {
                    unsigned m = (__float_as_uint(acc[mi][0][r]) & 0xFFFFFF80u) |
                                 ((unsigned)t << 2);
#pragma unroll
                    for (int nj = 1; nj < 4; ++nj) {
                        unsigned c = (__float_as_uint(acc[mi][nj][r]) & 0xFFFFFF80u) |
                                     ((unsigned)t << 2) | (unsigned)nj;
                        m = c > m ? c : m;
                    }
                    if (m > best[mi][r]) best[mi][r] = m;
                }
        } else {
            const int cb = colbase + (t << 7);
#pragma unroll
            for (int mi = 0; mi < 4; ++mi)
#pragma unroll
                for (int nj = 0; nj < 4; ++nj) {
                    const int gr16 = arow0 + (wr << 6) + (mi << 4);
                    const int gc16 = cb + (wc << 6) + (nj << 4);
                    if (gr16 == gc16) {
#pragma unroll
                        for (int r = 0; r < 4; ++r) {
                            const int rr = ((l >> 4) << 2) + r;
                            if ((l & 15) == rr) dg[gr16 + rr] = acc[mi][nj][r] * 10.0f;
                        }
                    }
                }
#pragma unroll
            for (int mi = 0; mi < 4; ++mi)
#pragma unroll
                for (int nj = 0; nj < 4; ++nj) {
                    v4f tv = acc[mi][nj];
                    tv[0] = exp2f(tv[0] * EXPSCALE);
                    tv[1] = exp2f(tv[1] * EXPSCALE);
                    tv[2] = exp2f(tv[2] * EXPSCALE);
                    tv[3] = exp2f(tv[3] * EXPSCALE);
                    acc[mi][nj] = tv;
                }
#pragma unroll
            for (int mi = 0; mi < 4; ++mi)
#pragma unroll
                for (int r = 0; r < 4; ++r) {
                    float s = 0.f;
#pragma unroll
                    for (int nj = 0; nj < 4; ++nj) s += acc[mi][nj][r];
                    rsum[mi][r] += s;
                }
#pragma unroll
            for (int nj = 0; nj < 4; ++nj) {
                float s = 0.f;
#pragma unroll
                for (int mi = 0; mi < 4; ++mi)
#pragma unroll
                    for (int r = 0; r < 4; ++r) s += acc[mi][nj][r];
                s += __shfl_xor(s, 16); s += __shfl_xor(s, 32);
                if (l < 16)
                    scp[((size_t)(z << 6) + (rowblk << 1) + wr) * BROWS +
                        cb + (wc << 6) + (nj << 4) + l] = s;
            }
        }
    }

    if (MODE == 0) {
#pragma unroll
        for (int mi = 0; mi < 4; ++mi)
#pragma unroll
            for (int r = 0; r < 4; ++r) {
                const unsigned wb = best[mi][r];
                const unsigned col = (unsigned)(colbase + (int)(((wb >> 2) & 31u) << 7) +
                                                (wc << 6) + (int)((wb & 3u) << 4)) + (l & 15);
                u64_t pk = ((u64_t)wb << 32) | (u64_t)(0xFFFFFFFFu - col);
#pragma unroll
                for (int off = 1; off < 16; off <<= 1) {
                    u64_t o = shfl_xor_u64(pk, off);
                    if (o > pk) pk = o;
                }
                if ((l & 15) == 0)
                    atomicMax(&pk_out[arow0 + (wr << 6) + (mi << 4) + ((l >> 4) << 2) + r], pk);
            }
    } else {
#pragma unroll
        for (int mi = 0; mi < 4; ++mi)
#pragma unroll
            for (int r = 0; r < 4; ++r) {
                float s = rsum[mi][r];
                s += __shfl_xor(s, 1); s += __shfl_xor(s, 2);
                s += __shfl_xor(s, 4); s += __shfl_xor(s, 8);
                if ((l & 15) == 0)
                    srp[((size_t)(z << 4) + (colstrip << 1) + wc) * BROWS +
                        arow0 + (wr << 6) + (mi << 4) + ((l >> 4) << 2) + r] = s;
            }
    }
}

// ---- fold partial strips into sums[4][BROWS] ----
__global__ __launch_bounds__(256) void reduce_sums(const float* __restrict__ srp,
                                                   const float* __restrict__ scp,
                                                   float* __restrict__ sums) {
    const int idx = blockIdx.x * 256 + threadIdx.x;   // 8192
    const int z = idx >> 12, row = idx & 4095;
    float a = 0.f, b = 0.f;
#pragma unroll 4
    for (int s = 0; s < 16; ++s) a += srp[((size_t)(z << 4) + s) * BROWS + row];
#pragma unroll 4
    for (int s = 0; s < 64; ++s) b += scp[((size_t)(z << 6) + s) * BROWS + row];
    sums[(size_t)(2 * z) * BROWS + row] = a;
    sums[(size_t)(2 * z + 1) * BROWS + row] = b;
}

// ---- gather nn rows: 8 rows/block-iter, 16B/lane ----
__global__ __launch_bounds__(256) void gather_bf(const u64_t* __restrict__ packed,
                                                 const ushort_t* __restrict__ qb,
                                                 ushort_t* __restrict__ nn) {
    const int r8 = threadIdx.x >> 5;   // 0..7
    const int c = threadIdx.x & 31;    // 32 chunks of 8 ushorts
    for (int base = blockIdx.x * 8; base < 2 * BROWS; base += (int)gridDim.x * 8) {
        const int i = base + r8;
        const unsigned idx = 0xFFFFFFFFu - (unsigned)(packed[i] & 0xFFFFFFFFull);
        *(v8us*)&nn[(size_t)i * DIMK + (c << 3)] =
            *(const v8us*)&qb[(size_t)idx * DIMK + (c << 3)];
    }
}

__global__ __launch_bounds__(256) void final_loss(const float* __restrict__ d1,
                                                  const float* __restrict__ d2,
                                                  const float* __restrict__ sr1,
                                                  const float* __restrict__ sc1,
                                                  const float* __restrict__ sr2,
                                                  const float* __restrict__ sc2,
                                                  float* __restrict__ out) {
    __shared__ float red[256];
    const int t = threadIdx.x;
    float acc = 0.f;
    for (int i = t; i < BROWS; i += 256) {
        acc += 2.f * (d1[i] + d2[i]) - logf(sr1[i]) - logf(sc1[i]) - logf(sr2[i]) - logf(sc2[i]);
    }
    red[t] = acc;
    __syncthreads();
    for (int s = 128; s > 0; s >>= 1) {
        if (t < s) red[t] += red[t + s];
        __syncthreads();
    }
    if (t == 0) out[0] = -red[0] / (4.0f * (float)BROWS);
}

extern "C" void kernel_launch(void* const* d_in, const int* in_sizes, int n_in,
                              void* d_out, int out_size, void* d_ws, size_t ws_size,
                              hipStream_t stream) {
    const float* f1 = (const float*)d_in[0];
    const float* f2 = (const float*)d_in[1];
    const float* W1 = (const float*)d_in[2];
    const float* b1 = (const float*)d_in[3];
    const float* W2 = (const float*)d_in[4];
    const float* b2 = (const float*)d_in[5];
    const float* queue = (const float*)d_in[6];
    float* out = (float*)d_out;

    char* ws = (char*)d_ws;
    ushort_t* pcat  = (ushort_t*)(ws + (8ull << 20));      // 4 MB: p1 | p2
    ushort_t* nncat = (ushort_t*)(ws + (12ull << 20));     // 4 MB: nn1 | nn2
    ushort_t* qb    = (ushort_t*)(ws + (16ull << 20));     // 16 MB
    u64_t* packed   = (u64_t*)(ws + (32ull << 20));        // 64 KB (8192 rows)
    float* sums     = (float*)(ws + (32ull << 20) + (64ull << 10));    // 64 KB
    float* diag     = (float*)(ws + (32ull << 20) + (128ull << 10));   // 32 KB
    float* srp      = (float*)(ws + (32ull << 20) + (160ull << 10));   // 512 KB
    float* scp      = (float*)(ws + (32ull << 20) + (672ull << 10));   // 2 MB

    hipMemsetAsync(packed, 0, (64ull << 10), stream);

    conv_bf16<<<(QN * DIMK) / 2048, 256, 0, stream>>>(queue, qb);

    dim3 gp(BROWS / 16, 2);
    proj_fused<<<gp, 256, 0, stream>>>(f1, f2, W1, b1, W2, b2, pcat);

    nn_lse<0, 32><<<512, 256, 0, stream>>>(pcat, qb, packed, nullptr, nullptr, nullptr);

    gather_bf<<<256, 256, 0, stream>>>(packed, qb, nncat);

    nn_lse<1, 4><<<512, 256, 0, stream>>>(nncat, pcat, nullptr, srp, scp, diag);

    reduce_sums<<<32, 256, 0, stream>>>(srp, scp, sums);

    final_loss<<<1, 256, 0, stream>>>(diag, diag + BROWS,
                                      sums, sums + BROWS, sums + 2 * BROWS, sums + 3 * BROWS,
                                      out);
}

// Round 13
// 244.553 us; speedup vs baseline: 1.1754x; 1.0823x over previous
//
#include <hip/hip_runtime.h>

typedef unsigned short ushort_t;
typedef unsigned long long u64_t;
typedef __attribute__((ext_vector_type(8))) short v8bf;
typedef __attribute__((ext_vector_type(8))) unsigned short v8us;
typedef __attribute__((ext_vector_type(4))) float v4f;

#define BROWS 4096
#define DIMK 256
#define QN 32768
#define EXPSCALE 14.426950408889634f   // 10 * log2(e)

__device__ __forceinline__ ushort_t f2bf(float f) {
    unsigned u = __float_as_uint(f);
    return (ushort_t)((u + 0x7FFFu + ((u >> 16) & 1u)) >> 16);   // RNE
}
__device__ __forceinline__ u64_t shfl_xor_u64(u64_t v, int off) {
    unsigned lo = (unsigned)(v & 0xFFFFFFFFull);
    unsigned hi = (unsigned)(v >> 32);
    lo = (unsigned)__shfl_xor((int)lo, off, 64);
    hi = (unsigned)__shfl_xor((int)hi, off, 64);
    return ((u64_t)hi << 32) | (u64_t)lo;
}
#define GLOAD(g, l_) __builtin_amdgcn_global_load_lds(                         \
    (const __attribute__((address_space(1))) void*)(g),                        \
    (__attribute__((address_space(3))) void*)(l_), 16, 0, 0)

// ---- bf16 conversion of the queue ----
__global__ __launch_bounds__(256) void conv_bf16(const float* __restrict__ in,
                                                 ushort_t* __restrict__ out) {
    const size_t i = ((size_t)blockIdx.x * 256 + threadIdx.x) * 8;
    float4 x = *(const float4*)&in[i];
    float4 y = *(const float4*)&in[i + 4];
    v8us o;
    o[0] = f2bf(x.x); o[1] = f2bf(x.y); o[2] = f2bf(x.z); o[3] = f2bf(x.w);
    o[4] = f2bf(y.x); o[5] = f2bf(y.y); o[6] = f2bf(y.z); o[7] = f2bf(y.w);
    *(v8us*)&out[i] = o;
}

// ---- fused two-layer projection + L2 norm (16 rows/block, grid.y = f1/f2) ----
__global__ __launch_bounds__(256) void proj_fused(const float* __restrict__ F1,
                                                  const float* __restrict__ F2,
                                                  const float* __restrict__ W1,
                                                  const float* __restrict__ b1,
                                                  const float* __restrict__ W2,
                                                  const float* __restrict__ b2,
                                                  ushort_t* __restrict__ P) {
    __shared__ float fr[16][256];
    __shared__ float hr[16][256];
    __shared__ float partial[4][16];
    const float* F = blockIdx.y ? F2 : F1;
    ushort_t* Po = P + (size_t)blockIdx.y * BROWS * DIMK;
    const int r0 = blockIdx.x << 4, j = threadIdx.x;
    const int w = j >> 6, l = j & 63;
#pragma unroll
    for (int r = 0; r < 16; ++r) fr[r][j] = F[(size_t)(r0 + r) * DIMK + j];
    __syncthreads();
    float acc[16];
    {
        const float bj = b1[j];
#pragma unroll
        for (int r = 0; r < 16; ++r) acc[r] = bj;
        for (int k = 0; k < DIMK; k += 4) {
            const float w0 = W1[(k + 0) * DIMK + j];
            const float w1 = W1[(k + 1) * DIMK + j];
            const float w2 = W1[(k + 2) * DIMK + j];
            const float w3 = W1[(k + 3) * DIMK + j];
#pragma unroll
            for (int r = 0; r < 16; ++r) {
                float4 f = *(const float4*)&fr[r][k];
                acc[r] = fmaf(f.x, w0, acc[r]);
                acc[r] = fmaf(f.y, w1, acc[r]);
                acc[r] = fmaf(f.z, w2, acc[r]);
                acc[r] = fmaf(f.w, w3, acc[r]);
            }
        }
#pragma unroll
        for (int r = 0; r < 16; ++r) hr[r][j] = acc[r] > 0.f ? acc[r] : 0.f;
    }
    __syncthreads();
    {
        const float bj = b2[j];
#pragma unroll
        for (int r = 0; r < 16; ++r) acc[r] = bj;
        for (int k = 0; k < DIMK; k += 4) {
            const float w0 = W2[(k + 0) * DIMK + j];
            const float w1 = W2[(k + 1) * DIMK + j];
            const float w2 = W2[(k + 2) * DIMK + j];
            const float w3 = W2[(k + 3) * DIMK + j];
#pragma unroll
            for (int r = 0; r < 16; ++r) {
                float4 f = *(const float4*)&hr[r][k];
                acc[r] = fmaf(f.x, w0, acc[r]);
                acc[r] = fmaf(f.y, w1, acc[r]);
                acc[r] = fmaf(f.z, w2, acc[r]);
                acc[r] = fmaf(f.w, w3, acc[r]);
            }
        }
    }
#pragma unroll
    for (int r = 0; r < 16; ++r) {
        float s = acc[r] * acc[r];
        s += __shfl_xor(s, 1);  s += __shfl_xor(s, 2);
        s += __shfl_xor(s, 4);  s += __shfl_xor(s, 8);
        s += __shfl_xor(s, 16); s += __shfl_xor(s, 32);
        if (l == 0) partial[w][r] = s;
    }
    __syncthreads();
#pragma unroll
    for (int r = 0; r < 16; ++r) {
        const float tot = partial[0][r] + partial[1][r] + partial[2][r] + partial[3][r];
        const float inv = 1.f / fmaxf(sqrtf(tot), 1e-12f);
        Po[(size_t)(r0 + r) * DIMK + j] = f2bf(acc[r] * inv);
    }
}

// ---- stage a 128-row x 256-k bf16 panel into 64KB LDS (64 segs of 1KB).
// Global source pre-swizzled: 16B slot s of row r holds octet (s&~7)|((s&7)^(r&7)).
__device__ __forceinline__ void stage_panel(const ushort_t* __restrict__ M, int grow0,
                                            ushort_t* lds, int w, int l) {
#pragma unroll
    for (int j = 0; j < 16; ++j) {
        const int seg = (j << 2) + w;
        const int row = (seg << 1) + (l >> 5);
        const int s = l & 31;
        const int oct = (s & ~7) | ((s & 7) ^ (row & 7));
        GLOAD(&M[(size_t)(grow0 + row) * DIMK + (oct << 3)], lds + (seg << 9));
    }
}

// ---- stage a 256-col x 32-k B tile (16KB, 64B rows). Pre-swizzled source:
// phys 16B slot s of row r holds logical octet s ^ ((r>>1)&3).
__device__ __forceinline__ void stage_b32(const ushort_t* __restrict__ B, int col0,
                                          int kelem, ushort_t* dst, int w, int l) {
#pragma unroll
    for (int j = 0; j < 4; ++j) {
        const int seg = (j << 2) + w;                 // 16 segs of 1KB (16 rows)
        const int row = (seg << 4) + (l >> 2);
        const int oct = (l & 3) ^ ((l >> 3) & 3);     // == (l&3) ^ ((row>>1)&3)
        GLOAD(&B[(size_t)(col0 + row) * DIMK + kelem + (oct << 3)], dst + (seg << 9));
    }
}

// ---- persistent-block GEMM (R9 shell, 64x128 wave tile).
// Block 128 rows x 256-col tiles, 4 waves (2Mx2N), wave tile 64x128 (acc 4x8).
// A panel (128x256) hoisted to LDS once; B tile (256 cols x 32 k, 16KB) staged
// per phase (single buffer, 2-barrier). LDS 64+16 = 80KB -> 2 blocks/CU.
// Per phase per CU: 96 ds_read_b128 (~1150cy) vs 256 MFMA (~1240cy) -> MFMA-bound
// (R9's 64x64 tile was LDS-bound at 128 reads vs 1240cy).
// MODE 0: fused argmax, 512 blocks persistent, NT=16 (4096 cols/block).
// MODE 1: exp-sums + diag, 512 blocks, NT=2, plain-store partials.
// NOTE: min-waves 2 (R7: 3 forced VGPR<=84 -> acc spill). Spill tripwire: if
// WRITE_SIZE >> KB (R12: areg spill = 27MB scratch), round invalid.
template <int MODE, int NT>
__global__ __launch_bounds__(256, 2) void nn_lse(const ushort_t* __restrict__ Abase,
                                                 const ushort_t* __restrict__ Bbase,
                                                 u64_t* __restrict__ packed,
                                                 float* __restrict__ srp,
                                                 float* __restrict__ scp,
                                                 float* __restrict__ diag) {
    __shared__ __align__(16) ushort_t Alds[128 * 256];   // 64 KB, staged once
    __shared__ __align__(16) ushort_t Bs[256 * 32];      // 16 KB, per phase
    const int tid = threadIdx.x;
    const int w = tid >> 6, l = tid & 63;
    const int wr = w >> 1, wc = w & 1;   // wave tile 64 rows x 128 cols

    int arow0, colbase, rowblk = 0, colstrip = 0, z = 0;
    const ushort_t* A; const ushort_t* B;
    u64_t* pk_out = nullptr;
    float* dg = nullptr;
    if (MODE == 0) {
        const int bid = blockIdx.x;                // 512 blocks, all resident
        const int xcd = bid & 7, i = bid >> 3;
        const int half = xcd & 1;
        const int pairgrp = xcd >> 1;              // owns 8192 cols
        arow0 = (i & 31) << 7;
        colbase = (pairgrp << 13) + ((i >> 5) << 12);
        A = Abase + (size_t)half * BROWS * DIMK;
        B = Bbase;
        pk_out = packed + (size_t)half * BROWS;
    } else {
        z = blockIdx.x >> 8;
        const int i = blockIdx.x & 255;
        rowblk = i & 31;
        colstrip = i >> 5;
        arow0 = rowblk << 7;
        colbase = colstrip << 9;
        A = Abase + (size_t)z * BROWS * DIMK;
        B = Bbase + (size_t)(1 - z) * BROWS * DIMK;
        dg = diag + (size_t)z * BROWS;
    }

    // A panel -> LDS once (drained by the first in-loop __syncthreads)
    stage_panel(A, arow0, (ushort_t*)Alds, w, l);

    unsigned best[4][4];
    float rsum[4][4];
#pragma unroll
    for (int a = 0; a < 4; ++a)
#pragma unroll
        for (int r = 0; r < 4; ++r) { best[a][r] = 0u; rsum[a][r] = 0.f; }

    for (int t = 0; t < NT; ++t) {
        v4f acc[4][8];
        const float cinit = (MODE == 0) ? 2.0f : 0.0f;   // +2 -> positive, uint-monotone
#pragma unroll
        for (int a = 0; a < 4; ++a)
#pragma unroll
            for (int b = 0; b < 8; ++b) acc[a][b] = (v4f){cinit, cinit, cinit, cinit};

#pragma unroll
        for (int k0 = 0; k0 < 8; ++k0) {          // K-phases of 32
            stage_b32(B, colbase + (t << 8), k0 << 5, (ushort_t*)Bs, w, l);
            __syncthreads();   // drains stage (and A panel on first pass)
            const int lo = l >> 4;                 // 0..3
            v8bf av[4], bv[8];
#pragma unroll
            for (int mi = 0; mi < 4; ++mi) {
                const int row = (wr << 6) + (mi << 4) + (l & 15);
                const int phys = ((k0 >> 1) << 3) | ((((k0 & 1) << 2) + lo) ^ (row & 7));
                av[mi] = *(const v8bf*)&Alds[(row << 8) + (phys << 3)];
            }
#pragma unroll
            for (int nj = 0; nj < 8; ++nj) {
                const int row = (wc << 7) + (nj << 4) + (l & 15);
                const int phys = lo ^ ((row >> 1) & 3);
                bv[nj] = *(const v8bf*)&Bs[(row << 5) + (phys << 3)];
            }
#pragma unroll
            for (int mi = 0; mi < 4; ++mi)
#pragma unroll
                for (int nj = 0; nj < 8; ++nj)
                    acc[mi][nj] = __builtin_amdgcn_mfma_f32_16x16x32_bf16(
                        av[mi], bv[nj], acc[mi][nj], 0, 0, 0);
            __syncthreads();   // all waves done reading Bs
        }

        if (MODE == 0) {
            // running argmax: (bits(v+2) & 0xFFFFFF80) | (t<<3) | nj, uint-max
#pragma unroll
            for (int mi = 0; mi < 4; ++mi)
#pragma unroll
                for (int r = 0; r < 4; ++r) {
                    unsigned m = (__float_as_uint(acc[mi][0][r]) & 0xFFFFFF80u) |
                                 ((unsigned)t << 3);
#pragma unroll
                    for (int nj = 1; nj < 8; ++nj) {
                        unsigned c = (__float_as_uint(acc[mi][nj][r]) & 0xFFFFFF80u) |
                                     ((unsigned)t << 3) | (unsigned)nj;
                        m = c > m ? c : m;
                    }
                    if (m > best[mi][r]) best[mi][r] = m;
                }
        } else {
            const int cb = colbase + (t << 8);
#pragma unroll
            for (int mi = 0; mi < 4; ++mi)
#pragma unroll
                for (int nj = 0; nj < 8; ++nj) {
                    const int gr16 = arow0 + (wr << 6) + (mi << 4);
                    const int gc16 = cb + (wc << 7) + (nj << 4);
                    if (gr16 == gc16) {
#pragma unroll
                        for (int r = 0; r < 4; ++r) {
                            const int rr = ((l >> 4) << 2) + r;
                            if ((l & 15) == rr) dg[gr16 + rr] = acc[mi][nj][r] * 10.0f;
                        }
                    }
                }
#pragma unroll
            for (int mi = 0; mi < 4; ++mi)
#pragma unroll
                for (int nj = 0; nj < 8; ++nj) {
                    v4f tv = acc[mi][nj];
                    tv[0] = exp2f(tv[0] * EXPSCALE);
                    tv[1] = exp2f(tv[1] * EXPSCALE);
                    tv[2] = exp2f(tv[2] * EXPSCALE);
                    tv[3] = exp2f(tv[3] * EXPSCALE);
                    acc[mi][nj] = tv;
                }
#pragma unroll
            for (int mi = 0; mi < 4; ++mi)
#pragma unroll
                for (int r = 0; r < 4; ++r) {
                    float s = 0.f;
#pragma unroll
                    for (int nj = 0; nj < 8; ++nj) s += acc[mi][nj][r];
                    rsum[mi][r] += s;
                }
            // col partials: unique strip (z,rowblk,wr); plain stores
#pragma unroll
            for (int nj = 0; nj < 8; ++nj) {
                float s = 0.f;
#pragma unroll
                for (int mi = 0; mi < 4; ++mi)
#pragma unroll
                    for (int r = 0; r < 4; ++r) s += acc[mi][nj][r];
                s += __shfl_xor(s, 16); s += __shfl_xor(s, 32);
                if (l < 16)
                    scp[((size_t)(z << 6) + (rowblk << 1) + wr) * BROWS +
                        cb + (wc << 7) + (nj << 4) + l] = s;
            }
        }
    }

    if (MODE == 0) {
#pragma unroll
        for (int mi = 0; mi < 4; ++mi)
#pragma unroll
            for (int r = 0; r < 4; ++r) {
                const unsigned wb = best[mi][r];
                const unsigned col = (unsigned)(colbase + (int)(((wb >> 3) & 15u) << 8) +
                                                (wc << 7) + (int)((wb & 7u) << 4)) + (l & 15);
                u64_t pk = ((u64_t)wb << 32) | (u64_t)(0xFFFFFFFFu - col);
#pragma unroll
                for (int off = 1; off < 16; off <<= 1) {
                    u64_t o = shfl_xor_u64(pk, off);
                    if (o > pk) pk = o;
                }
                if ((l & 15) == 0)
                    atomicMax(&pk_out[arow0 + (wr << 6) + (mi << 4) + ((l >> 4) << 2) + r], pk);
            }
    } else {
        // row partials: unique strip (z, colstrip, wc); plain stores
#pragma unroll
        for (int mi = 0; mi < 4; ++mi)
#pragma unroll
            for (int r = 0; r < 4; ++r) {
                float s = rsum[mi][r];
                s += __shfl_xor(s, 1); s += __shfl_xor(s, 2);
                s += __shfl_xor(s, 4); s += __shfl_xor(s, 8);
                if ((l & 15) == 0)
                    srp[((size_t)(z << 4) + (colstrip << 1) + wc) * BROWS +
                        arow0 + (wr << 6) + (mi << 4) + ((l >> 4) << 2) + r] = s;
            }
    }
}

// ---- fold partial strips into sums[4][BROWS] ----
__global__ __launch_bounds__(256) void reduce_sums(const float* __restrict__ srp,
                                                   const float* __restrict__ scp,
                                                   float* __restrict__ sums) {
    const int idx = blockIdx.x * 256 + threadIdx.x;   // 8192
    const int z = idx >> 12, row = idx & 4095;
    float a = 0.f, b = 0.f;
#pragma unroll 4
    for (int s = 0; s < 16; ++s) a += srp[((size_t)(z << 4) + s) * BROWS + row];
#pragma unroll 4
    for (int s = 0; s < 64; ++s) b += scp[((size_t)(z << 6) + s) * BROWS + row];
    sums[(size_t)(2 * z) * BROWS + row] = a;
    sums[(size_t)(2 * z + 1) * BROWS + row] = b;
}

// ---- gather nn rows: 8 rows/block-iter, 16B/lane ----
__global__ __launch_bounds__(256) void gather_bf(const u64_t* __restrict__ packed,
                                                 const ushort_t* __restrict__ qb,
                                                 ushort_t* __restrict__ nn) {
    const int r8 = threadIdx.x >> 5;   // 0..7
    const int c = threadIdx.x & 31;    // 32 chunks of 8 ushorts
    for (int base = blockIdx.x * 8; base < 2 * BROWS; base += (int)gridDim.x * 8) {
        const int i = base + r8;
        const unsigned idx = 0xFFFFFFFFu - (unsigned)(packed[i] & 0xFFFFFFFFull);
        *(v8us*)&nn[(size_t)i * DIMK + (c << 3)] =
            *(const v8us*)&qb[(size_t)idx * DIMK + (c << 3)];
    }
}

__global__ __launch_bounds__(256) void final_loss(const float* __restrict__ d1,
                                                  const float* __restrict__ d2,
                                                  const float* __restrict__ sr1,
                                                  const float* __restrict__ sc1,
                                                  const float* __restrict__ sr2,
                                                  const float* __restrict__ sc2,
                                                  float* __restrict__ out) {
    __shared__ float red[256];
    const int t = threadIdx.x;
    float acc = 0.f;
    for (int i = t; i < BROWS; i += 256) {
        acc += 2.f * (d1[i] + d2[i]) - logf(sr1[i]) - logf(sc1[i]) - logf(sr2[i]) - logf(sc2[i]);
    }
    red[t] = acc;
    __syncthreads();
    for (int s = 128; s > 0; s >>= 1) {
        if (t < s) red[t] += red[t + s];
        __syncthreads();
    }
    if (t == 0) out[0] = -red[0] / (4.0f * (float)BROWS);
}

extern "C" void kernel_launch(void* const* d_in, const int* in_sizes, int n_in,
                              void* d_out, int out_size, void* d_ws, size_t ws_size,
                              hipStream_t stream) {
    const float* f1 = (const float*)d_in[0];
    const float* f2 = (const float*)d_in[1];
    const float* W1 = (const float*)d_in[2];
    const float* b1 = (const float*)d_in[3];
    const float* W2 = (const float*)d_in[4];
    const float* b2 = (const float*)d_in[5];
    const float* queue = (const float*)d_in[6];
    float* out = (float*)d_out;

    char* ws = (char*)d_ws;
    ushort_t* pcat  = (ushort_t*)(ws + (8ull << 20));      // 4 MB: p1 | p2
    ushort_t* nncat = (ushort_t*)(ws + (12ull << 20));     // 4 MB: nn1 | nn2
    ushort_t* qb    = (ushort_t*)(ws + (16ull << 20));     // 16 MB
    u64_t* packed   = (u64_t*)(ws + (32ull << 20));        // 64 KB (8192 rows)
    float* sums     = (float*)(ws + (32ull << 20) + (64ull << 10));    // 64 KB
    float* diag     = (float*)(ws + (32ull << 20) + (128ull << 10));   // 32 KB
    float* srp      = (float*)(ws + (32ull << 20) + (160ull << 10));   // 512 KB
    float* scp      = (float*)(ws + (32ull << 20) + (672ull << 10));   // 2 MB

    hipMemsetAsync(packed, 0, (64ull << 10), stream);

    conv_bf16<<<(QN * DIMK) / 2048, 256, 0, stream>>>(queue, qb);

    dim3 gp(BROWS / 16, 2);
    proj_fused<<<gp, 256, 0, stream>>>(f1, f2, W1, b1, W2, b2, pcat);

    nn_lse<0, 16><<<512, 256, 0, stream>>>(pcat, qb, packed, nullptr, nullptr, nullptr);

    gather_bf<<<256, 256, 0, stream>>>(packed, qb, nncat);

    nn_lse<1, 2><<<512, 256, 0, stream>>>(nncat, pcat, nullptr, srp, scp, diag);

    reduce_sums<<<32, 256, 0, stream>>>(srp, scp, sums);

    final_loss<<<1, 256, 0, stream>>>(diag, diag + BROWS,
                                      sums, sums + BROWS, sums + 2 * BROWS, sums + 3 * BROWS,
                                      out);
}